// Round 5
// baseline (8898.416 us; speedup 1.0000x reference)
//
#include <hip/hip_runtime.h>

typedef unsigned short u16;
typedef unsigned int u32;

#define CC_    256         // channels
#define NHD_   8           // heads
#define NT_    64          // tokens per window
#define HD_    32          // head dim
#define HID_   1024        // mlp hidden
#define CPBH_  512         // cpb hidden
#define BW_    2048        // total windows = 32 * 64
#define TOK_   131072      // total tokens
#define SHIFT_ 4

// region id (0..8) in the shifted canvas for mask construction
__device__ __forceinline__ int region9(int ph, int pw) {
  return (ph < 56 ? 0 : (ph < 60 ? 3 : 6)) + (pw < 56 ? 0 : (pw < 60 ? 1 : 2));
}
__device__ __forceinline__ float dot32(const float* qr, const float* krow) {
  float d0 = 0.f, d1 = 0.f, d2 = 0.f, d3 = 0.f;
#pragma unroll
  for (int d = 0; d < HD_; d += 4) {
    float4 kk = *reinterpret_cast<const float4*>(krow + d);
    d0 += qr[d] * kk.x; d1 += qr[d + 1] * kk.y;
    d2 += qr[d + 2] * kk.z; d3 += qr[d + 3] * kk.w;
  }
  return (d0 + d1) + (d2 + d3);
}

// ---------------- kernel 1: CPB MLP -> bias_table[225][8] ----------------
__global__ void cpb_kernel(const float* __restrict__ w1, const float* __restrict__ b1,
                           const float* __restrict__ w2, float* __restrict__ bias_table) {
  __shared__ float hid[CPBH_];
  int p = blockIdx.x;        // 0..224
  int k = threadIdx.x;       // 0..511
  int hi = p / 15, wi = p % 15;
  float a0 = (float)(hi - 7) / 7.0f * 8.0f;
  float a1 = (float)(wi - 7) / 7.0f * 8.0f;
  float t0 = (a0 == 0.0f) ? 0.0f : copysignf(log2f(fabsf(a0) + 1.0f) / 3.0f, a0);
  float t1 = (a1 == 0.0f) ? 0.0f : copysignf(log2f(fabsf(a1) + 1.0f) / 3.0f, a1);
  float h = t0 * w1[2 * k] + t1 * w1[2 * k + 1] + b1[k];
  hid[k] = fmaxf(h, 0.0f);
  __syncthreads();
  if (k < NHD_) {
    float s = 0.0f;
    for (int j = 0; j < CPBH_; j++) s += hid[j] * w2[k * CPBH_ + j];
    bias_table[p * NHD_ + k] = s;
  }
}

// ---------------- kernel 2: gather + sigmoid -> rpb[8][64][64] ----------------
__global__ void rpb_kernel(const float* __restrict__ bias_table, float* __restrict__ rpb) {
  int h = blockIdx.x >> 6;   // grid 512
  int i = blockIdx.x & 63;
  int j = threadIdx.x;       // 64
  int dih = (i >> 3) - (j >> 3) + 7;
  int diw = (i & 7) - (j & 7) + 7;
  float v = bias_table[(dih * 15 + diw) * NHD_ + h];
  rpb[(((h << 6) + i) << 6) + j] = 16.0f / (1.0f + expf(-v));
}

// ---------------- kernel 3: shifted-window gather + QKV GEMM (chunk of windows) ----------------
__global__ __launch_bounds__(256) void qkv_kernel(
    const float* __restrict__ x, const float* __restrict__ qkvw,
    const float* __restrict__ qb, const float* __restrict__ vb,
    float* __restrict__ qo, float* __restrict__ ko, float* __restrict__ vo, int w0) {
  __shared__ float xs[8][CC_];
  int blk = blockIdx.x;          // nw*8
  int wl = blk >> 3;             // chunk-local window
  int w = w0 + wl;               // global window
  int n0 = (blk & 7) << 3;       // first token in window
  int tid = threadIdx.x;
  int b = w >> 6, win = w & 63;
  int wh = win >> 3, ww = win & 7;
  for (int t = 0; t < 8; t++) {
    int n = n0 + t;
    int sh = wh * 8 + (n >> 3), sw = ww * 8 + (n & 7);
    int hh = (sh + SHIFT_) & 63, wc = (sw + SHIFT_) & 63;
    size_t src = ((size_t)((b << 12) + (hh << 6) + wc)) * CC_;
    xs[t][tid] = x[src + tid];
  }
  __syncthreads();
  int oc = tid;
  float accq[8], acck[8], accv[8];
#pragma unroll
  for (int t = 0; t < 8; t++) { accq[t] = 0.f; acck[t] = 0.f; accv[t] = 0.f; }
  const float* wq = qkvw + (size_t)oc * CC_;
  const float* wk = qkvw + (size_t)(oc + CC_) * CC_;
  const float* wv = qkvw + (size_t)(oc + 2 * CC_) * CC_;
  for (int c0 = 0; c0 < CC_; c0 += 4) {
    float4 fq = *reinterpret_cast<const float4*>(wq + c0);
    float4 fk = *reinterpret_cast<const float4*>(wk + c0);
    float4 fv = *reinterpret_cast<const float4*>(wv + c0);
#pragma unroll
    for (int t = 0; t < 8; t++) {
      float4 xt = *reinterpret_cast<const float4*>(&xs[t][c0]);
      accq[t] += xt.x * fq.x + xt.y * fq.y + xt.z * fq.z + xt.w * fq.w;
      acck[t] += xt.x * fk.x + xt.y * fk.y + xt.z * fk.z + xt.w * fk.w;
      accv[t] += xt.x * fv.x + xt.y * fv.y + xt.z * fv.z + xt.w * fv.w;
    }
  }
  float bq = qb[oc], bv = vb[oc];
  int hh = oc >> 5, d = oc & 31;
  for (int t = 0; t < 8; t++) {
    int n = n0 + t;
    size_t idx = ((size_t)(wl * NHD_ + hh) * NT_ + n) * HD_ + d;  // chunk-local
    qo[idx] = accq[t] + bq;
    ko[idx] = acck[t];
    vo[idx] = accv[t] + bv;
  }
}

// ---------------- kernel 4: windowed cosine attention (chunk-local in and out) ----------------
__global__ __launch_bounds__(64) void attn_kernel(
    const float* __restrict__ qq, const float* __restrict__ kk_, const float* __restrict__ vv_,
    const float* __restrict__ ls, const float* __restrict__ rpb, float* __restrict__ attn_out, int w0) {
  __shared__ float ks[NT_][HD_];
  __shared__ float vs[NT_][HD_];
  int bid = blockIdx.x;          // nw*8 = wl*NH+h
  int wl = bid >> 3, h = bid & 7;
  int w = w0 + wl;               // global window
  int i = threadIdx.x;           // 64
  size_t base = (size_t)bid * (NT_ * HD_) + (size_t)i * HD_;  // chunk-local

  float qr[HD_];
  float ss = 0.f;
#pragma unroll
  for (int d = 0; d < HD_; d += 4) {
    float4 f = *reinterpret_cast<const float4*>(qq + base + d);
    qr[d] = f.x; qr[d + 1] = f.y; qr[d + 2] = f.z; qr[d + 3] = f.w;
    ss += f.x * f.x + f.y * f.y + f.z * f.z + f.w * f.w;
  }
  float inv = 1.0f / fmaxf(sqrtf(ss), 1e-12f);
#pragma unroll
  for (int d = 0; d < HD_; d++) qr[d] *= inv;

  float kr[HD_]; ss = 0.f;
#pragma unroll
  for (int d = 0; d < HD_; d += 4) {
    float4 f = *reinterpret_cast<const float4*>(kk_ + base + d);
    kr[d] = f.x; kr[d + 1] = f.y; kr[d + 2] = f.z; kr[d + 3] = f.w;
    ss += f.x * f.x + f.y * f.y + f.z * f.z + f.w * f.w;
  }
  inv = 1.0f / fmaxf(sqrtf(ss), 1e-12f);
#pragma unroll
  for (int d = 0; d < HD_; d += 4) {
    float4 t; t.x = kr[d] * inv; t.y = kr[d + 1] * inv; t.z = kr[d + 2] * inv; t.w = kr[d + 3] * inv;
    *reinterpret_cast<float4*>(&ks[i][d]) = t;
  }
#pragma unroll
  for (int d = 0; d < HD_; d += 4) {
    float4 f = *reinterpret_cast<const float4*>(vv_ + base + d);
    *reinterpret_cast<float4*>(&vs[i][d]) = f;
  }
  __syncthreads();

  float scale = expf(fminf(ls[h], 4.605170185988091f));  // clamp at log(100)
  const float* rp = rpb + (((h << 6) + i) << 6);
  int win = w & 63, wh = win >> 3, ww = win & 7;
  int regi = region9(wh * 8 + (i >> 3), ww * 8 + (i & 7));

  // pass 1: online max + denom
  float m = -1e30f, l = 0.f;
  for (int j = 0; j < NT_; j++) {
    float dot = dot32(qr, &ks[j][0]);
    int regj = region9(wh * 8 + (j >> 3), ww * 8 + (j & 7));
    float val = dot * scale + rp[j] + (regj == regi ? 0.f : -100.f);
    float nm = fmaxf(m, val);
    l = l * expf(m - nm) + expf(val - nm);
    m = nm;
  }
  float rl = 1.0f / l;

  // pass 2: recompute probs, accumulate P·V
  float acc[HD_];
#pragma unroll
  for (int d = 0; d < HD_; d++) acc[d] = 0.f;
  for (int j = 0; j < NT_; j++) {
    float dot = dot32(qr, &ks[j][0]);
    int regj = region9(wh * 8 + (j >> 3), ww * 8 + (j & 7));
    float val = dot * scale + rp[j] + (regj == regi ? 0.f : -100.f);
    float p = expf(val - m) * rl;
#pragma unroll
    for (int d = 0; d < HD_; d += 4) {
      float4 vvv = *reinterpret_cast<const float4*>(&vs[j][d]);
      acc[d] += p * vvv.x; acc[d + 1] += p * vvv.y; acc[d + 2] += p * vvv.z; acc[d + 3] += p * vvv.w;
    }
  }
  // chunk-local token index; layout [n, C] per window
  float* op = attn_out + ((size_t)(wl * NT_ + i)) * CC_ + h * HD_;
#pragma unroll
  for (int d = 0; d < HD_; d += 4) {
    float4 t; t.x = acc[d]; t.y = acc[d + 1]; t.z = acc[d + 2]; t.w = acc[d + 3];
    *reinterpret_cast<float4*>(op + d) = t;
  }
}

// ---------------- kernel 5: proj + window-reverse + LN(norm1) + residual -> x1 (= d_out, fp32) ----------------
__global__ __launch_bounds__(256) void proj_kernel(
    const float* __restrict__ attn_out, const float* __restrict__ pw, const float* __restrict__ pb,
    const float* __restrict__ g, const float* __restrict__ bb,
    const float* __restrict__ x, float* __restrict__ x1, int w0) {
  __shared__ float as_[8][CC_];
  __shared__ float ps[8][CC_];
  int blk = blockIdx.x;          // nw*8
  int wl = blk >> 3;
  int w = w0 + wl;
  int n0 = (blk & 7) << 3;
  int tid = threadIdx.x;
  for (int t = 0; t < 8; t++)
    as_[t][tid] = attn_out[((size_t)(wl * NT_ + n0 + t)) * CC_ + tid];  // chunk-local
  __syncthreads();
  float acc[8];
#pragma unroll
  for (int t = 0; t < 8; t++) acc[t] = 0.f;
  const float* wr = pw + (size_t)tid * CC_;
  for (int c0 = 0; c0 < CC_; c0 += 4) {
    float4 f = *reinterpret_cast<const float4*>(wr + c0);
#pragma unroll
    for (int t = 0; t < 8; t++) {
      float4 xt = *reinterpret_cast<const float4*>(&as_[t][c0]);
      acc[t] += xt.x * f.x + xt.y * f.y + xt.z * f.z + xt.w * f.w;
    }
  }
  float pbv = pb[tid];
#pragma unroll
  for (int t = 0; t < 8; t++) ps[t][tid] = acc[t] + pbv;
  __syncthreads();

  int wv = tid >> 6, lane = tid & 63;
  int b = w >> 6, win = w & 63, wh = win >> 3, ww = win & 7;
  for (int tt = 0; tt < 2; tt++) {
    int t = wv * 2 + tt;
    int n = n0 + t;
    float sum = 0.f, sq = 0.f;
#pragma unroll
    for (int kk = 0; kk < 4; kk++) { float v = ps[t][lane + 64 * kk]; sum += v; sq += v * v; }
#pragma unroll
    for (int off = 1; off < 64; off <<= 1) {
      sum += __shfl_xor(sum, off, 64);
      sq  += __shfl_xor(sq, off, 64);
    }
    float mean = sum * (1.0f / CC_);
    float var = sq * (1.0f / CC_) - mean * mean;
    float rs = rsqrtf(fmaxf(var, 0.0f) + 1e-5f);
    int sh = wh * 8 + (n >> 3), sw = ww * 8 + (n & 7);
    int hh = (sh + SHIFT_) & 63, wc = (sw + SHIFT_) & 63;
    size_t tok = ((size_t)b << 12) + (hh << 6) + wc;
#pragma unroll
    for (int kk = 0; kk < 4; kk++) {
      int c = lane + 64 * kk;
      float y = (ps[t][c] - mean) * rs * g[c] + bb[c];
      x1[tok * CC_ + c] = x[tok * CC_ + c] + y;
    }
  }
}

// ---------------- kernel 6: MLP (fc1+gelu+fc2) + LN(norm2) + residual; in-place on d_out ----------------
__global__ __launch_bounds__(256) void mlp_kernel(
    const float* __restrict__ x1,
    const float* __restrict__ w1, const float* __restrict__ b1,
    const float* __restrict__ w2, const float* __restrict__ b2,
    const float* __restrict__ g, const float* __restrict__ bb, float* __restrict__ out) {
  __shared__ float xs[8][CC_];
  __shared__ float hid[8][HID_];
  __shared__ float po[8][CC_];
  int tid = threadIdx.x;
  size_t t0 = (size_t)blockIdx.x * 8;
  for (int t = 0; t < 8; t++) xs[t][tid] = x1[(t0 + t) * CC_ + tid];
  __syncthreads();
  for (int jj = 0; jj < 4; jj++) {
    int j = tid + (jj << 8);
    float acc[8];
#pragma unroll
    for (int t = 0; t < 8; t++) acc[t] = 0.f;
    const float* wr = w1 + (size_t)j * CC_;
    for (int c0 = 0; c0 < CC_; c0 += 4) {
      float4 f = *reinterpret_cast<const float4*>(wr + c0);
#pragma unroll
      for (int t = 0; t < 8; t++) {
        float4 xt = *reinterpret_cast<const float4*>(&xs[t][c0]);
        acc[t] += xt.x * f.x + xt.y * f.y + xt.z * f.z + xt.w * f.w;
      }
    }
    float bv = b1[j];
#pragma unroll
    for (int t = 0; t < 8; t++) {
      float xg = acc[t] + bv;
      hid[t][j] = 0.5f * xg * (1.0f + erff(xg * 0.7071067811865475f));
    }
  }
  __syncthreads();
  float acc2[8];
#pragma unroll
  for (int t = 0; t < 8; t++) acc2[t] = 0.f;
  const float* wr2 = w2 + (size_t)tid * HID_;
  for (int c0 = 0; c0 < HID_; c0 += 4) {
    float4 f = *reinterpret_cast<const float4*>(wr2 + c0);
#pragma unroll
    for (int t = 0; t < 8; t++) {
      float4 ht = *reinterpret_cast<const float4*>(&hid[t][c0]);
      acc2[t] += ht.x * f.x + ht.y * f.y + ht.z * f.z + ht.w * f.w;
    }
  }
  float bv2 = b2[tid];
#pragma unroll
  for (int t = 0; t < 8; t++) po[t][tid] = acc2[t] + bv2;
  __syncthreads();

  int wv = tid >> 6, lane = tid & 63;
  for (int tt = 0; tt < 2; tt++) {
    int t = wv * 2 + tt;
    float sum = 0.f, sq = 0.f;
#pragma unroll
    for (int kk = 0; kk < 4; kk++) { float v = po[t][lane + 64 * kk]; sum += v; sq += v * v; }
#pragma unroll
    for (int off = 1; off < 64; off <<= 1) {
      sum += __shfl_xor(sum, off, 64);
      sq  += __shfl_xor(sq, off, 64);
    }
    float mean = sum * (1.0f / CC_);
    float var = sq * (1.0f / CC_) - mean * mean;
    float rs = rsqrtf(fmaxf(var, 0.0f) + 1e-5f);
#pragma unroll
    for (int kk = 0; kk < 4; kk++) {
      int c = lane + 64 * kk;
      float y = (po[t][c] - mean) * rs * g[c] + bb[c];
      out[(t0 + t) * CC_ + c] = xs[t][c] + y;
    }
  }
}

extern "C" void kernel_launch(void* const* d_in, const int* in_sizes, int n_in,
                              void* d_out, int out_size, void* d_ws, size_t ws_size,
                              hipStream_t stream) {
  const float* x       = (const float*)d_in[0];
  const float* qkv_w   = (const float*)d_in[1];
  const float* q_bias  = (const float*)d_in[2];
  const float* v_bias  = (const float*)d_in[3];
  const float* logit_s = (const float*)d_in[4];
  const float* cpb_w1  = (const float*)d_in[5];
  const float* cpb_b1  = (const float*)d_in[6];
  const float* cpb_w2  = (const float*)d_in[7];
  const float* proj_w  = (const float*)d_in[8];
  const float* proj_b  = (const float*)d_in[9];
  const float* n1g     = (const float*)d_in[10];
  const float* n1b     = (const float*)d_in[11];
  const float* n2g     = (const float*)d_in[12];
  const float* n2b     = (const float*)d_in[13];
  const float* fc1_w   = (const float*)d_in[14];
  const float* fc1_b   = (const float*)d_in[15];
  const float* fc2_w   = (const float*)d_in[16];
  const float* fc2_b   = (const float*)d_in[17];
  float* out = (float*)d_out;
  char* ws = (char*)d_ws;

  // Workspace layout (minimum need: 139264 + 1*262144 bytes ~ 400 KB):
  //   [0,      8192): bias_table (fp32, 7200B used)
  //   [8192, 139264): rpb        (fp32, 8*64*64)
  //   [139264, ...):  per-chunk q,k,v,attn_out (fp32), nc windows each
  // x1 lives in d_out (fp32, exactly TOK_*CC_ elements); mlp_kernel updates
  // d_out in place (each block reads only the 8 tokens it overwrites).
  const size_t OFF_CH = 139264;
  const size_t ELEM_PER_WIN = (size_t)NHD_ * NT_ * HD_;      // 16384 fp32 elems per buffer per window
  const size_t PER_WIN_BYTES = 4 * ELEM_PER_WIN * 4;         // q+k+v+attn = 262144 B/window

  float* bias_table = (float*)(ws);
  float* rpb        = (float*)(ws + 8192);

  long long avail = (long long)ws_size - (long long)OFF_CH;
  long long ncw = avail / (long long)PER_WIN_BYTES;
  if (ncw < 1) ncw = 1;
  if (ncw > BW_) ncw = BW_;
  int nc = (int)ncw;   // windows per chunk — depends only on ws_size (graph-safe)

  float* qc = (float*)(ws + OFF_CH);
  float* kc = qc + (size_t)nc * ELEM_PER_WIN;
  float* vc = kc + (size_t)nc * ELEM_PER_WIN;
  float* ac = vc + (size_t)nc * ELEM_PER_WIN;

  cpb_kernel<<<225, 512, 0, stream>>>(cpb_w1, cpb_b1, cpb_w2, bias_table);
  rpb_kernel<<<NHD_ * NT_, 64, 0, stream>>>(bias_table, rpb);

  for (int w0 = 0; w0 < BW_; w0 += nc) {
    int nw = (BW_ - w0 < nc) ? (BW_ - w0) : nc;
    qkv_kernel<<<nw * 8, 256, 0, stream>>>(x, qkv_w, q_bias, v_bias, qc, kc, vc, w0);
    attn_kernel<<<nw * 8, 64, 0, stream>>>(qc, kc, vc, logit_s, rpb, ac, w0);
    proj_kernel<<<nw * 8, 256, 0, stream>>>(ac, proj_w, proj_b, n1g, n1b, x, out, w0);
  }
  mlp_kernel<<<TOK_ / 8, 256, 0, stream>>>(out, fc1_w, fc1_b, fc2_w, fc2_b, n2g, n2b, out);
}